// Round 14
// baseline (250.679 us; speedup 1.0000x reference)
//
#include <hip/hip_runtime.h>
#include <hip/hip_bf16.h>
#include <cstdint>

typedef __attribute__((ext_vector_type(8))) short short8_t;   // 8 x bf16
typedef __attribute__((ext_vector_type(4))) short short4_t;   // 4 x bf16
typedef __attribute__((ext_vector_type(4))) float f32x4_t;    // MFMA acc

#define AS1 __attribute__((address_space(1)))
#define AS3 __attribute__((address_space(3)))

__device__ __forceinline__ void gload_lds16(const void* g, void* l) {
  __builtin_amdgcn_global_load_lds((const AS1 void*)g, (AS3 void*)l, 16, 0, 0);
}

__device__ __forceinline__ short8_t ld8(const __hip_bfloat16* p) {
  return *(const short8_t*)p;
}

// ---------------- fused prep: convert x + transpose all 7 weights ----------------
__global__ __launch_bounds__(256) void k_prep(
    const float* __restrict__ x, __hip_bfloat16* __restrict__ xb,
    const float* __restrict__ wq,  const float* __restrict__ wqp,
    const float* __restrict__ wkp, const float* __restrict__ wdkv,
    const float* __restrict__ wuk, const float* __restrict__ wuv,
    const float* __restrict__ wo,
    __hip_bfloat16* __restrict__ Bt1, __hip_bfloat16* __restrict__ Bt2,
    __hip_bfloat16* __restrict__ woT) {
  __shared__ float t[64][65];
  int bid = blockIdx.x;
  if (bid < 4096) {
    int i = (bid * 256 + threadIdx.x) * 8;
    union { short8_t v; __hip_bfloat16 h[8]; } u;
#pragma unroll
    for (int j = 0; j < 8; ++j) u.h[j] = __float2bfloat16(x[i + j]);
    *(short8_t*)(xb + i) = u.v;
    return;
  }
  bid -= 4096;
  const float* in; __hip_bfloat16* out; int R, C, tile;
  if (bid < 1024)      { in = wq;   out = Bt1;                 R = 2048; C = 2048; tile = bid; }
  else if (bid < 1536) { in = wqp;  out = Bt1 + 2048UL * 2048; R = 2048; C = 1024; tile = bid - 1024; }
  else if (bid < 2048) { in = wkp;  out = Bt1 + 3072UL * 2048; R = 2048; C = 1024; tile = bid - 1536; }
  else if (bid < 2304) { in = wdkv; out = Bt1 + 4096UL * 2048; R = 2048; C = 512;  tile = bid - 2048; }
  else if (bid < 2560) { in = wuk;  out = Bt2;                 R = 512;  C = 2048; tile = bid - 2304; }
  else if (bid < 2816) { in = wuv;  out = Bt2 + 2048UL * 512;  R = 512;  C = 2048; tile = bid - 2560; }
  else                 { in = wo;   out = woT;                 R = 2048; C = 2048; tile = bid - 2816; }
  int nct = C >> 6;
  int ct = tile % nct, rt = tile / nct;
  int r0 = rt << 6, c0 = ct << 6;
#pragma unroll
  for (int i = 0; i < 16; ++i) {
    int idx = i * 256 + threadIdx.x;
    int r = idx >> 6, c = idx & 63;
    t[r][c] = in[(size_t)(r0 + r) * C + c0 + c];
  }
  __syncthreads();
#pragma unroll
  for (int i = 0; i < 16; ++i) {
    int idx = i * 256 + threadIdx.x;
    int c = idx >> 6, r = idx & 63;
    out[(size_t)(c0 + c) * R + r0 + r] = __float2bfloat16(t[r][c]);
  }
}

// ---------------- ring-3 pipelined GEMM (R5-proven): 128x128, 4 waves, 48 KB LDS ----
// MODE 1: f32 out.
template<int MODE>
__global__ __launch_bounds__(256) void k_gemm2(const __hip_bfloat16* __restrict__ A,
                                               const __hip_bfloat16* __restrict__ Bt,
                                               int K, int nbx,
                                               void* __restrict__ O0, float alpha) {
  __shared__ __align__(16) __hip_bfloat16 Al[3][128 * 32];
  __shared__ __align__(16) __hip_bfloat16 Bl[3][128 * 32];
  int bx = blockIdx.x % nbx, by = blockIdx.x / nbx;
  int tid = threadIdx.x, lane = tid & 63, w = tid >> 6;
  int L = lane & 15, hi = lane >> 4;
  int wr = (w >> 1) << 6, wc = (w & 1) << 6;
  f32x4_t acc[4][4] = {};
  const __hip_bfloat16* Ag = A + (size_t)(by * 128) * K;
  const __hip_bfloat16* Bg = Bt + (size_t)(bx * 128) * K;
  int rA = w * 16 + (lane >> 2);
  int cA = ((lane & 3) ^ ((lane >> 3) & 3)) * 8;       // inverse-swizzled source chunk
  int NT = K >> 5;

  auto stage = [&](int s) {
    int j = s % 3;
    int k0 = s << 5;
    gload_lds16(Ag + (size_t)rA * K + k0 + cA,        &Al[j][(w * 16) * 32]);
    gload_lds16(Ag + (size_t)(rA + 64) * K + k0 + cA, &Al[j][(64 + w * 16) * 32]);
    gload_lds16(Bg + (size_t)rA * K + k0 + cA,        &Bl[j][(w * 16) * 32]);
    gload_lds16(Bg + (size_t)(rA + 64) * K + k0 + cA, &Bl[j][(64 + w * 16) * 32]);
  };

  stage(0); stage(1);
  asm volatile("s_waitcnt vmcnt(4)\ns_barrier" ::: "memory");

  int hs = hi ^ ((L >> 1) & 3);
  for (int t = 0; t < NT; ++t) {
    int j = t % 3;
    short8_t af[4], bf[4];
#pragma unroll
    for (int m = 0; m < 4; ++m) af[m] = ld8(&Al[j][(wr + 16 * m + L) * 32 + 8 * hs]);
#pragma unroll
    for (int n = 0; n < 4; ++n) bf[n] = ld8(&Bl[j][(wc + 16 * n + L) * 32 + 8 * hs]);
    if (t + 2 < NT) stage(t + 2);
    __builtin_amdgcn_s_setprio(1);
#pragma unroll
    for (int m = 0; m < 4; ++m)
#pragma unroll
      for (int n = 0; n < 4; ++n)
        acc[m][n] = __builtin_amdgcn_mfma_f32_16x16x32_bf16(af[m], bf[n], acc[m][n], 0, 0, 0);
    __builtin_amdgcn_s_setprio(0);
    if (t + 2 < NT)      asm volatile("s_waitcnt vmcnt(4)\ns_barrier" ::: "memory");
    else if (t + 1 < NT) asm volatile("s_waitcnt vmcnt(0)\ns_barrier" ::: "memory");
  }

  int r0 = by * 128 + wr + 4 * hi;
  int c0 = bx * 128 + wc;
  size_t N = (size_t)nbx << 7;
  float* C = (float*)O0;
#pragma unroll
  for (int m = 0; m < 4; ++m)
#pragma unroll
    for (int n = 0; n < 4; ++n)
#pragma unroll
      for (int i = 0; i < 4; ++i)
        C[(size_t)(r0 + 16 * m + i) * N + c0 + 16 * n + L] = acc[m][n][i] * alpha;
}

// ---------------- split-K ring-3 GEMM for wdkv: 256 blocks = 2 K-parts x 128 tiles ----
__global__ __launch_bounds__(256) void k_gemm_ks(const __hip_bfloat16* __restrict__ A,
                                                 const __hip_bfloat16* __restrict__ Bt,
                                                 int lda, int nbx,
                                                 float* __restrict__ P0,
                                                 float* __restrict__ P1) {
  __shared__ __align__(16) __hip_bfloat16 Al[3][128 * 32];
  __shared__ __align__(16) __hip_bfloat16 Bl[3][128 * 32];
  int part = blockIdx.x >> 7;
  int id = blockIdx.x & 127;
  int bx = id % nbx, by = id / nbx;
  int tid = threadIdx.x, lane = tid & 63, w = tid >> 6;
  int L = lane & 15, hi = lane >> 4;
  int wr = (w >> 1) << 6, wc = (w & 1) << 6;
  f32x4_t acc[4][4] = {};
  const __hip_bfloat16* Ag = A + (size_t)(by * 128) * lda + part * 1024;
  const __hip_bfloat16* Bg = Bt + (size_t)(bx * 128) * lda + part * 1024;
  int rA = w * 16 + (lane >> 2);
  int cA = ((lane & 3) ^ ((lane >> 3) & 3)) * 8;
  const int NT = 32;                                    // K=1024

  auto stage = [&](int s) {
    int j = s % 3;
    int k0 = s << 5;
    gload_lds16(Ag + (size_t)rA * lda + k0 + cA,        &Al[j][(w * 16) * 32]);
    gload_lds16(Ag + (size_t)(rA + 64) * lda + k0 + cA, &Al[j][(64 + w * 16) * 32]);
    gload_lds16(Bg + (size_t)rA * lda + k0 + cA,        &Bl[j][(w * 16) * 32]);
    gload_lds16(Bg + (size_t)(rA + 64) * lda + k0 + cA, &Bl[j][(64 + w * 16) * 32]);
  };

  stage(0); stage(1);
  asm volatile("s_waitcnt vmcnt(4)\ns_barrier" ::: "memory");

  int hs = hi ^ ((L >> 1) & 3);
  for (int t = 0; t < NT; ++t) {
    int j = t % 3;
    short8_t af[4], bf[4];
#pragma unroll
    for (int m = 0; m < 4; ++m) af[m] = ld8(&Al[j][(wr + 16 * m + L) * 32 + 8 * hs]);
#pragma unroll
    for (int n = 0; n < 4; ++n) bf[n] = ld8(&Bl[j][(wc + 16 * n + L) * 32 + 8 * hs]);
    if (t + 2 < NT) stage(t + 2);
    __builtin_amdgcn_s_setprio(1);
#pragma unroll
    for (int m = 0; m < 4; ++m)
#pragma unroll
      for (int n = 0; n < 4; ++n)
        acc[m][n] = __builtin_amdgcn_mfma_f32_16x16x32_bf16(af[m], bf[n], acc[m][n], 0, 0, 0);
    __builtin_amdgcn_s_setprio(0);
    if (t + 2 < NT)      asm volatile("s_waitcnt vmcnt(4)\ns_barrier" ::: "memory");
    else if (t + 1 < NT) asm volatile("s_waitcnt vmcnt(0)\ns_barrier" ::: "memory");
  }

  float* C = part ? P1 : P0;
  int r0 = by * 128 + wr + 4 * hi;
  int c0 = bx * 128 + wc;
#pragma unroll
  for (int m = 0; m < 4; ++m)
#pragma unroll
    for (int n = 0; n < 4; ++n)
#pragma unroll
      for (int i = 0; i < 4; ++i)
        C[(size_t)(r0 + 16 * m + i) * 512 + c0 + 16 * n + L] = acc[m][n][i];
}

// ---------------- combine split-K partials -> bf16 ckv ----------------
__global__ __launch_bounds__(256) void k_addc(const float* __restrict__ P0,
                                              const float* __restrict__ P1,
                                              __hip_bfloat16* __restrict__ ckv) {
  int i = (blockIdx.x * 256 + threadIdx.x) * 4;        // 2097152 elems / 4
  float4 a = *(const float4*)(P0 + i);
  float4 b = *(const float4*)(P1 + i);
  union { short4_t v; __hip_bfloat16 h[4]; } u;
  u.h[0] = __float2bfloat16(a.x + b.x);
  u.h[1] = __float2bfloat16(a.y + b.y);
  u.h[2] = __float2bfloat16(a.z + b.z);
  u.h[3] = __float2bfloat16(a.w + b.w);
  *(short4_t*)(ckv + i) = u.v;
}

// ---------------- ring-2 BIG GEMM: 256x256, BK=32, 8 waves, 64 KB LDS -> 2 blocks/CU ----
// R12-proven body; ring depth 3->2 (stage 1 ahead, gate vmcnt(0)+barrier after MFMA).
// Buffer safety: stage(t+1) writes buf[(t+1)&1] != buf[t&1] being read; end-of-iter
// barrier orders cross-wave reuse.
template<int MODE>
__global__ __launch_bounds__(512, 2) void k_gemm8(const __hip_bfloat16* __restrict__ A,
                                                  const __hip_bfloat16* __restrict__ Bt,
                                                  int K, int nbx,
                                                  void* __restrict__ O0, void* __restrict__ O1,
                                                  void* __restrict__ O2) {
  __shared__ __align__(16) __hip_bfloat16 Al[2][256 * 32];   // 32 KB
  __shared__ __align__(16) __hip_bfloat16 Bl[2][256 * 32];   // 32 KB
  int bx = blockIdx.x % nbx, by = blockIdx.x / nbx;
  int tid = threadIdx.x, lane = tid & 63, w = tid >> 6;      // w: 0..7
  int L = lane & 15, hi = lane >> 4;
  int wr = (w >> 2) << 7;                                    // 0 or 128
  int wc = (w & 3) << 6;                                     // 0,64,128,192
  f32x4_t acc[8][4] = {};
  const __hip_bfloat16* Ag = A + (size_t)(by * 256) * K;
  const __hip_bfloat16* Bg = Bt + (size_t)(bx * 256) * K;
  int rA = w * 16 + (lane >> 2);                             // 0..127
  int cA = ((lane & 3) ^ ((lane >> 3) & 3)) * 8;
  int NT = K >> 5;

  auto stage = [&](int s) {
    int j = s & 1;
    int k0 = s << 5;
    gload_lds16(Ag + (size_t)rA * K + k0 + cA,         &Al[j][(w * 16) * 32]);
    gload_lds16(Ag + (size_t)(rA + 128) * K + k0 + cA, &Al[j][(128 + w * 16) * 32]);
    gload_lds16(Bg + (size_t)rA * K + k0 + cA,         &Bl[j][(w * 16) * 32]);
    gload_lds16(Bg + (size_t)(rA + 128) * K + k0 + cA, &Bl[j][(128 + w * 16) * 32]);
  };

  stage(0);
  asm volatile("s_waitcnt vmcnt(0)\ns_barrier" ::: "memory");

  int hs = hi ^ ((L >> 1) & 3);
  for (int t = 0; t < NT; ++t) {
    int j = t & 1;
    short8_t af[8], bf[4];
#pragma unroll
    for (int m = 0; m < 8; ++m) af[m] = ld8(&Al[j][(wr + 16 * m + L) * 32 + 8 * hs]);
#pragma unroll
    for (int n = 0; n < 4; ++n) bf[n] = ld8(&Bl[j][(wc + 16 * n + L) * 32 + 8 * hs]);
    if (t + 1 < NT) stage(t + 1);
    __builtin_amdgcn_s_setprio(1);
#pragma unroll
    for (int m = 0; m < 8; ++m)
#pragma unroll
      for (int n = 0; n < 4; ++n)
        acc[m][n] = __builtin_amdgcn_mfma_f32_16x16x32_bf16(af[m], bf[n], acc[m][n], 0, 0, 0);
    __builtin_amdgcn_s_setprio(0);
    if (t + 1 < NT) asm volatile("s_waitcnt vmcnt(0)\ns_barrier" ::: "memory");
  }

  int r0 = by * 256 + wr + 4 * hi;
  int cb = bx * 256 + wc;

  if (MODE == 2) {
    // proj1-main: cols 0-2047 q_c*SCALE -> qcb; 2048-3071 q_r rope; 3072-4095 k_r rope
    __hip_bfloat16* qcb = (__hip_bfloat16*)O0;
    __hip_bfloat16* qrb = (__hip_bfloat16*)O1;
    __hip_bfloat16* krb = (__hip_bfloat16*)O2;
    if (cb < 2048) {
      const float SCALE = 0.08838834764831845f;
#pragma unroll
      for (int m = 0; m < 8; ++m)
#pragma unroll
        for (int n = 0; n < 4; ++n)
#pragma unroll
          for (int i = 0; i < 4; ++i)
            qcb[(size_t)(r0 + 16 * m + i) * 2048 + cb + 16 * n + L] =
                __float2bfloat16(acc[m][n][i] * SCALE);
    } else {
      bool isq = cb < 3072;
      __hip_bfloat16* dst = isq ? qrb : krb;
      float osc = isq ? 0.16832169878499666f : 1.3465735902799727f;  // SCALE_ROPE*YF : YF
      int cbl = cb - (isq ? 2048 : 3072);
      float invf[2];
#pragma unroll
      for (int p = 0; p < 2; ++p) {
        float fi = (float)(16 * p + L);
        float bi = __expf(fi * -0.28782313662425574f);   // 10000^(-i/32)
        float ramp = fminf(fmaxf((fi - 1.0f) * (1.0f / 31.0f), 0.0f), 1.0f);
        invf[p] = bi * (1.0f - ramp * (31.0f / 32.0f));
      }
#pragma unroll
      for (int m = 0; m < 8; ++m)
#pragma unroll
        for (int i = 0; i < 4; ++i) {
          int row = r0 + 16 * m + i;
          float ft = (float)(row & 2047);
#pragma unroll
          for (int p = 0; p < 2; ++p) {
            float sn, cs;
            __sincosf(ft * invf[p], &sn, &cs);
            float x1 = acc[m][p][i], x2 = acc[m][p + 2][i];
            dst[(size_t)row * 1024 + cbl + 16 * p + L] =
                __float2bfloat16((x1 * cs - x2 * sn) * osc);
            dst[(size_t)row * 1024 + cbl + 32 + 16 * p + L] =
                __float2bfloat16((x2 * cs + x1 * sn) * osc);
          }
        }
    }
  } else if (MODE == 3) {
    // proj2: cols 0-2047 k_c -> kcb; 2048-4095 v_c -> vcb AND vT transposed
    __hip_bfloat16* kcb = (__hip_bfloat16*)O0;
    __hip_bfloat16* vcb = (__hip_bfloat16*)O1;
    __hip_bfloat16* vT  = (__hip_bfloat16*)O2;
    if (cb < 2048) {
#pragma unroll
      for (int m = 0; m < 8; ++m)
#pragma unroll
        for (int n = 0; n < 4; ++n)
#pragma unroll
          for (int i = 0; i < 4; ++i)
            kcb[(size_t)(r0 + 16 * m + i) * 2048 + cb + 16 * n + L] =
                __float2bfloat16(acc[m][n][i]);
    } else {
#pragma unroll
      for (int m = 0; m < 8; ++m)
#pragma unroll
        for (int n = 0; n < 4; ++n) {
          int vcol = cb - 2048 + 16 * n + L;      // 0..2047: h*128+dh
          int hh = vcol >> 7, dh = vcol & 127;
          int row0 = r0 + 16 * m;                 // 4 consecutive rows, same b
          int b = row0 >> 11, t0 = row0 & 2047;
          union { short4_t v; __hip_bfloat16 h4[4]; } pk;
#pragma unroll
          for (int i = 0; i < 4; ++i) {
            __hip_bfloat16 bv = __float2bfloat16(acc[m][n][i]);
            vcb[(size_t)(row0 + i) * 2048 + vcol] = bv;
            pk.h4[i] = bv;
          }
          *(short4_t*)(vT + ((size_t)((b * 16 + hh) * 128 + dh) * 2048 + t0)) = pk.v;
        }
    }
  }
}

// ---------------- flash-style SPARSE attention (R13-proven, unchanged) ----------------
__global__ __launch_bounds__(256) void k_attn(const __hip_bfloat16* __restrict__ qc,
                                              const __hip_bfloat16* __restrict__ kc,
                                              const __hip_bfloat16* __restrict__ vcb,
                                              const __hip_bfloat16* __restrict__ qr,
                                              const __hip_bfloat16* __restrict__ kr,
                                              const __hip_bfloat16* __restrict__ vT,
                                              __hip_bfloat16* __restrict__ ao) {
  const int T = 2048;
  int bid = blockIdx.x;
  int qt = 31 - (bid >> 5);        // true LPT: heaviest q-tiles dispatched first
  int bh = bid & 31;
  int b = bh >> 4, h = bh & 15;
  int tid = threadIdx.x, lane = tid & 63, w = tid >> 6;
  int L = lane & 15, hi = lane >> 4;
  int q0 = qt * 64;

  __shared__ __align__(16) __hip_bfloat16 Kl[64 * 200];
  __shared__ __align__(16) __hip_bfloat16 Vt[128 * 64];
  __shared__ __align__(16) __hip_bfloat16 Pl[4][16 * 72];

  char* Vtb = (char*)Vt;
  const __hip_bfloat16* vTb = vT + (size_t)(b * 16 + h) * 128 * 2048;

  int qrow = q0 + w * 16 + L;
  size_t qb = (size_t)b * T + qrow;
  short8_t qf[6];
#pragma unroll
  for (int c = 0; c < 4; ++c)
    qf[c] = ld8(qc + qb * 2048 + h * 128 + 32 * c + 8 * hi);
#pragma unroll
  for (int c = 0; c < 2; ++c)
    qf[4 + c] = ld8(qr + qb * 1024 + h * 64 + 32 * c + 8 * hi);

  f32x4_t oacc[8] = {};
  float lpart[4] = {0.0f, 0.0f, 0.0f, 0.0f};

  int nd = qt - 6;

  for (int step = 0; step <= qt + 1; ++step) {
    bool compact = (step == qt + 1);
    if (compact && nd <= 0) break;
    int kt = step;
    if (!compact && kt > 1 && kt < qt - 4) continue;
    int k0 = kt * 64;

    if (!compact) {
#pragma unroll
      for (int i = 0; i < 6; ++i) {
        int ch = i * 256 + tid;
        int rr = ch / 24;
        int d = (ch % 24) * 8;
        size_t krow = (size_t)b * T + k0 + rr;
        const __hip_bfloat16* src = (d < 128)
            ? kc + krow * 2048 + h * 128 + d
            : kr + krow * 1024 + h * 64 + (d - 128);
        *(short8_t*)(Kl + rr * 200 + d) = ld8(src);
      }
#pragma unroll
      for (int i = 0; i < 4; ++i) {
        int ch = i * 256 + tid;
        int row = ch >> 3, c = ch & 7;
        int swc = c ^ (row & 7);
        *(short8_t*)(Vtb + row * 128 + 16 * swc) = ld8(vTb + (size_t)row * 2048 + k0 + c * 8);
      }
    } else {
#pragma unroll
      for (int i = 0; i < 6; ++i) {
        int ch = i * 256 + tid;
        int rr = ch / 24;
        int d = (ch % 24) * 8;
        int srcr = (rr < nd) ? 64 * (2 + rr) : 0;
        size_t krow = (size_t)b * T + srcr;
        const __hip_bfloat16* src = (d < 128)
            ? kc + krow * 2048 + h * 128 + d
            : kr + krow * 1024 + h * 64 + (d - 128);
        *(short8_t*)(Kl + rr * 200 + d) = ld8(src);
      }
#pragma unroll
      for (int i = 0; i < 2; ++i) {
        int ch = i * 256 + tid;
        int jj = ch >> 4, d0 = (ch & 15) * 8;
        if (jj < nd) {
          union { short8_t v; __hip_bfloat16 hh[8]; } u;
          u.v = ld8(vcb + (size_t)(b * 2048 + 64 * (2 + jj)) * 2048 + h * 128 + d0);
#pragma unroll
          for (int qq = 0; qq < 8; ++qq) {
            int dh = d0 + qq;
            int swc = (jj >> 3) ^ (dh & 7);
            *(__hip_bfloat16*)(Vtb + dh * 128 + 16 * swc + 2 * (jj & 7)) = u.hh[qq];
          }
        }
      }
    }
    __syncthreads();

    f32x4_t sacc[4] = {};
    __builtin_amdgcn_s_setprio(1);
#pragma unroll
    for (int n = 0; n < 4; ++n)
#pragma unroll
      for (int c = 0; c < 6; ++c) {
        short8_t bfr = ld8(Kl + (16 * n + L) * 200 + 32 * c + 8 * hi);
        sacc[n] = __builtin_amdgcn_mfma_f32_16x16x32_bf16(qf[c], bfr, sacc[n], 0, 0, 0);
      }
    __builtin_amdgcn_s_setprio(0);

    int rbase = q0 + w * 16 + 4 * hi;
#pragma unroll
    for (int n = 0; n < 4; ++n) {
      int col = L + 16 * n;
      int k = k0 + col;
#pragma unroll
      for (int i = 0; i < 4; ++i) {
        int rq = rbase + i;
        bool ok = compact ? (col < nd)
                          : ((k <= rq) && ((rq - k <= 256) || ((k & 63) == 0) || (k < 128)));
        float e = ok ? __expf(sacc[n][i]) : 0.0f;
        lpart[i] += e;
        Pl[w][(4 * hi + i) * 72 + 16 * n + L] = __float2bfloat16(e);
      }
    }

    __builtin_amdgcn_s_setprio(1);
#pragma unroll
    for (int ks = 0; ks < 2; ++ks) {
      short8_t pa = ld8(Pl[w] + L * 72 + 32 * ks + 8 * hi);
#pragma unroll
      for (int n = 0; n < 8; ++n) {
        int vrow = 16 * n + L;
        int chunk = (4 * ks + hi) ^ (vrow & 7);
        short8_t bv = *(const short8_t*)(Vtb + vrow * 128 + 16 * chunk);
        oacc[n] = __builtin_amdgcn_mfma_f32_16x16x32_bf16(pa, bv, oacc[n], 0, 0, 0);
      }
    }
    __builtin_amdgcn_s_setprio(0);
    __syncthreads();
  }

  for (int d = 1; d < 16; d <<= 1)
#pragma unroll
    for (int i = 0; i < 4; ++i) lpart[i] += __shfl_xor(lpart[i], d, 64);

#pragma unroll
  for (int n = 0; n < 8; ++n)
#pragma unroll
    for (int i = 0; i < 4; ++i) {
      int rq = q0 + w * 16 + 4 * hi + i;
      int cdh = 16 * n + L;
      float v = oacc[n][i] / lpart[i];
      ao[((size_t)b * T + rq) * 2048 + h * 128 + cdh] = __float2bfloat16(v);
    }
}

// ---------------- host ----------------
extern "C" void kernel_launch(void* const* d_in, const int* in_sizes, int n_in,
                              void* d_out, int out_size, void* d_ws, size_t ws_size,
                              hipStream_t stream) {
  const float* x     = (const float*)d_in[0];
  const float* w_q   = (const float*)d_in[1];
  const float* w_dkv = (const float*)d_in[2];
  const float* w_uk  = (const float*)d_in[3];
  const float* w_uv  = (const float*)d_in[4];
  const float* w_qp  = (const float*)d_in[5];
  const float* w_kp  = (const float*)d_in[6];
  const float* w_o   = (const float*)d_in[7];
  float* out = (float*)d_out;

  char* ws = (char*)d_ws;
  size_t off = 0;
  auto alloc = [&](size_t elems) {
    __hip_bfloat16* p = (__hip_bfloat16*)(ws + off);
    off += ((elems * 2 + 255) & ~(size_t)255);
    return p;
  };
  __hip_bfloat16* xb  = alloc(8388608);            // x bf16 [4096][2048]
  __hip_bfloat16* Bt1 = alloc(4608UL * 2048);      // [wq^T; wqp^T; wkp^T; wdkv^T]
  __hip_bfloat16* Bt2 = alloc(4096UL * 512);       // [wuk^T; wuv^T]
  __hip_bfloat16* woT = alloc(4194304);
  __hip_bfloat16* qcb = alloc(8388608);
  __hip_bfloat16* ckv = alloc(2097152);
  __hip_bfloat16* kcb = alloc(8388608);
  __hip_bfloat16* vcb = alloc(8388608);
  __hip_bfloat16* qrb = alloc(4194304);
  __hip_bfloat16* krb = alloc(4194304);
  __hip_bfloat16* aob = alloc(8388608);            // attn out; reused as wdkv f32 partials
  __hip_bfloat16* vT  = alloc(8388608);            // [32][128][2048]

  float* P0 = (float*)aob;
  float* P1 = P0 + 2097152;

  k_prep<<<7936, 256, 0, stream>>>(x, xb, w_q, w_qp, w_kp, w_dkv, w_uk, w_uv, w_o,
                                   Bt1, Bt2, woT);

  k_gemm_ks<<<256, 256, 0, stream>>>(xb, Bt1 + 4096UL * 2048, 2048, 4, P0, P1);
  k_addc<<<2048, 256, 0, stream>>>(P0, P1, ckv);

  k_gemm8<2><<<16 * 16, 512, 0, stream>>>(xb, Bt1, 2048, 16, qcb, qrb, krb);
  k_gemm8<3><<<16 * 16, 512, 0, stream>>>(ckv, Bt2, 512, 16, kcb, vcb, vT);

  k_attn<<<1024, 256, 0, stream>>>(qcb, kcb, vcb, qrb, krb, vT, aob);

  k_gemm2<1><<<16 * 32, 256, 0, stream>>>(aob, woT, 2048, 16, out, 1.0f);
}

// Round 15
// 248.463 us; speedup vs baseline: 1.0089x; 1.0089x over previous
//
#include <hip/hip_runtime.h>
#include <hip/hip_bf16.h>
#include <cstdint>

typedef __attribute__((ext_vector_type(8))) short short8_t;   // 8 x bf16
typedef __attribute__((ext_vector_type(4))) short short4_t;   // 4 x bf16
typedef __attribute__((ext_vector_type(4))) float f32x4_t;    // MFMA acc

#define AS1 __attribute__((address_space(1)))
#define AS3 __attribute__((address_space(3)))

__device__ __forceinline__ void gload_lds16(const void* g, void* l) {
  __builtin_amdgcn_global_load_lds((const AS1 void*)g, (AS3 void*)l, 16, 0, 0);
}

__device__ __forceinline__ short8_t ld8(const __hip_bfloat16* p) {
  return *(const short8_t*)p;
}

// ---------------- fused prep: convert x + transpose all 7 weights ----------------
__global__ __launch_bounds__(256) void k_prep(
    const float* __restrict__ x, __hip_bfloat16* __restrict__ xb,
    const float* __restrict__ wq,  const float* __restrict__ wqp,
    const float* __restrict__ wkp, const float* __restrict__ wdkv,
    const float* __restrict__ wuk, const float* __restrict__ wuv,
    const float* __restrict__ wo,
    __hip_bfloat16* __restrict__ Bt1, __hip_bfloat16* __restrict__ Bt2,
    __hip_bfloat16* __restrict__ woT) {
  __shared__ float t[64][65];
  int bid = blockIdx.x;
  if (bid < 4096) {
    int i = (bid * 256 + threadIdx.x) * 8;
    union { short8_t v; __hip_bfloat16 h[8]; } u;
#pragma unroll
    for (int j = 0; j < 8; ++j) u.h[j] = __float2bfloat16(x[i + j]);
    *(short8_t*)(xb + i) = u.v;
    return;
  }
  bid -= 4096;
  const float* in; __hip_bfloat16* out; int R, C, tile;
  if (bid < 1024)      { in = wq;   out = Bt1;                 R = 2048; C = 2048; tile = bid; }
  else if (bid < 1536) { in = wqp;  out = Bt1 + 2048UL * 2048; R = 2048; C = 1024; tile = bid - 1024; }
  else if (bid < 2048) { in = wkp;  out = Bt1 + 3072UL * 2048; R = 2048; C = 1024; tile = bid - 1536; }
  else if (bid < 2304) { in = wdkv; out = Bt1 + 4096UL * 2048; R = 2048; C = 512;  tile = bid - 2048; }
  else if (bid < 2560) { in = wuk;  out = Bt2;                 R = 512;  C = 2048; tile = bid - 2304; }
  else if (bid < 2816) { in = wuv;  out = Bt2 + 2048UL * 512;  R = 512;  C = 2048; tile = bid - 2560; }
  else                 { in = wo;   out = woT;                 R = 2048; C = 2048; tile = bid - 2816; }
  int nct = C >> 6;
  int ct = tile % nct, rt = tile / nct;
  int r0 = rt << 6, c0 = ct << 6;
#pragma unroll
  for (int i = 0; i < 16; ++i) {
    int idx = i * 256 + threadIdx.x;
    int r = idx >> 6, c = idx & 63;
    t[r][c] = in[(size_t)(r0 + r) * C + c0 + c];
  }
  __syncthreads();
#pragma unroll
  for (int i = 0; i < 16; ++i) {
    int idx = i * 256 + threadIdx.x;
    int c = idx >> 6, r = idx & 63;
    out[(size_t)(c0 + c) * R + r0 + r] = __float2bfloat16(t[r][c]);
  }
}

// ---------------- ring-3 pipelined GEMM (R5-proven): 128x128, 4 waves, 48 KB LDS ----
// MODE 1: f32 out.
template<int MODE>
__global__ __launch_bounds__(256) void k_gemm2(const __hip_bfloat16* __restrict__ A,
                                               const __hip_bfloat16* __restrict__ Bt,
                                               int K, int nbx,
                                               void* __restrict__ O0, float alpha) {
  __shared__ __align__(16) __hip_bfloat16 Al[3][128 * 32];
  __shared__ __align__(16) __hip_bfloat16 Bl[3][128 * 32];
  int bx = blockIdx.x % nbx, by = blockIdx.x / nbx;
  int tid = threadIdx.x, lane = tid & 63, w = tid >> 6;
  int L = lane & 15, hi = lane >> 4;
  int wr = (w >> 1) << 6, wc = (w & 1) << 6;
  f32x4_t acc[4][4] = {};
  const __hip_bfloat16* Ag = A + (size_t)(by * 128) * K;
  const __hip_bfloat16* Bg = Bt + (size_t)(bx * 128) * K;
  int rA = w * 16 + (lane >> 2);
  int cA = ((lane & 3) ^ ((lane >> 3) & 3)) * 8;       // inverse-swizzled source chunk
  int NT = K >> 5;

  auto stage = [&](int s) {
    int j = s % 3;
    int k0 = s << 5;
    gload_lds16(Ag + (size_t)rA * K + k0 + cA,        &Al[j][(w * 16) * 32]);
    gload_lds16(Ag + (size_t)(rA + 64) * K + k0 + cA, &Al[j][(64 + w * 16) * 32]);
    gload_lds16(Bg + (size_t)rA * K + k0 + cA,        &Bl[j][(w * 16) * 32]);
    gload_lds16(Bg + (size_t)(rA + 64) * K + k0 + cA, &Bl[j][(64 + w * 16) * 32]);
  };

  stage(0); stage(1);
  asm volatile("s_waitcnt vmcnt(4)\ns_barrier" ::: "memory");

  int hs = hi ^ ((L >> 1) & 3);
  for (int t = 0; t < NT; ++t) {
    int j = t % 3;
    short8_t af[4], bf[4];
#pragma unroll
    for (int m = 0; m < 4; ++m) af[m] = ld8(&Al[j][(wr + 16 * m + L) * 32 + 8 * hs]);
#pragma unroll
    for (int n = 0; n < 4; ++n) bf[n] = ld8(&Bl[j][(wc + 16 * n + L) * 32 + 8 * hs]);
    if (t + 2 < NT) stage(t + 2);
    __builtin_amdgcn_s_setprio(1);
#pragma unroll
    for (int m = 0; m < 4; ++m)
#pragma unroll
      for (int n = 0; n < 4; ++n)
        acc[m][n] = __builtin_amdgcn_mfma_f32_16x16x32_bf16(af[m], bf[n], acc[m][n], 0, 0, 0);
    __builtin_amdgcn_s_setprio(0);
    if (t + 2 < NT)      asm volatile("s_waitcnt vmcnt(4)\ns_barrier" ::: "memory");
    else if (t + 1 < NT) asm volatile("s_waitcnt vmcnt(0)\ns_barrier" ::: "memory");
  }

  int r0 = by * 128 + wr + 4 * hi;
  int c0 = bx * 128 + wc;
  size_t N = (size_t)nbx << 7;
  float* C = (float*)O0;
#pragma unroll
  for (int m = 0; m < 4; ++m)
#pragma unroll
    for (int n = 0; n < 4; ++n)
#pragma unroll
      for (int i = 0; i < 4; ++i)
        C[(size_t)(r0 + 16 * m + i) * N + c0 + 16 * n + L] = acc[m][n][i] * alpha;
}

// ---------------- split-K ring-3 GEMM for wdkv: 256 blocks = 2 K-parts x 128 tiles ----
__global__ __launch_bounds__(256) void k_gemm_ks(const __hip_bfloat16* __restrict__ A,
                                                 const __hip_bfloat16* __restrict__ Bt,
                                                 int lda, int nbx,
                                                 float* __restrict__ P0,
                                                 float* __restrict__ P1) {
  __shared__ __align__(16) __hip_bfloat16 Al[3][128 * 32];
  __shared__ __align__(16) __hip_bfloat16 Bl[3][128 * 32];
  int part = blockIdx.x >> 7;
  int id = blockIdx.x & 127;
  int bx = id % nbx, by = id / nbx;
  int tid = threadIdx.x, lane = tid & 63, w = tid >> 6;
  int L = lane & 15, hi = lane >> 4;
  int wr = (w >> 1) << 6, wc = (w & 1) << 6;
  f32x4_t acc[4][4] = {};
  const __hip_bfloat16* Ag = A + (size_t)(by * 128) * lda + part * 1024;
  const __hip_bfloat16* Bg = Bt + (size_t)(bx * 128) * lda + part * 1024;
  int rA = w * 16 + (lane >> 2);
  int cA = ((lane & 3) ^ ((lane >> 3) & 3)) * 8;
  const int NT = 32;                                    // K=1024

  auto stage = [&](int s) {
    int j = s % 3;
    int k0 = s << 5;
    gload_lds16(Ag + (size_t)rA * lda + k0 + cA,        &Al[j][(w * 16) * 32]);
    gload_lds16(Ag + (size_t)(rA + 64) * lda + k0 + cA, &Al[j][(64 + w * 16) * 32]);
    gload_lds16(Bg + (size_t)rA * lda + k0 + cA,        &Bl[j][(w * 16) * 32]);
    gload_lds16(Bg + (size_t)(rA + 64) * lda + k0 + cA, &Bl[j][(64 + w * 16) * 32]);
  };

  stage(0); stage(1);
  asm volatile("s_waitcnt vmcnt(4)\ns_barrier" ::: "memory");

  int hs = hi ^ ((L >> 1) & 3);
  for (int t = 0; t < NT; ++t) {
    int j = t % 3;
    short8_t af[4], bf[4];
#pragma unroll
    for (int m = 0; m < 4; ++m) af[m] = ld8(&Al[j][(wr + 16 * m + L) * 32 + 8 * hs]);
#pragma unroll
    for (int n = 0; n < 4; ++n) bf[n] = ld8(&Bl[j][(wc + 16 * n + L) * 32 + 8 * hs]);
    if (t + 2 < NT) stage(t + 2);
    __builtin_amdgcn_s_setprio(1);
#pragma unroll
    for (int m = 0; m < 4; ++m)
#pragma unroll
      for (int n = 0; n < 4; ++n)
        acc[m][n] = __builtin_amdgcn_mfma_f32_16x16x32_bf16(af[m], bf[n], acc[m][n], 0, 0, 0);
    __builtin_amdgcn_s_setprio(0);
    if (t + 2 < NT)      asm volatile("s_waitcnt vmcnt(4)\ns_barrier" ::: "memory");
    else if (t + 1 < NT) asm volatile("s_waitcnt vmcnt(0)\ns_barrier" ::: "memory");
  }

  float* C = part ? P1 : P0;
  int r0 = by * 128 + wr + 4 * hi;
  int c0 = bx * 128 + wc;
#pragma unroll
  for (int m = 0; m < 4; ++m)
#pragma unroll
    for (int n = 0; n < 4; ++n)
#pragma unroll
      for (int i = 0; i < 4; ++i)
        C[(size_t)(r0 + 16 * m + i) * 512 + c0 + 16 * n + L] = acc[m][n][i];
}

// ---------------- combine split-K partials -> bf16 ckv ----------------
__global__ __launch_bounds__(256) void k_addc(const float* __restrict__ P0,
                                              const float* __restrict__ P1,
                                              __hip_bfloat16* __restrict__ ckv) {
  int i = (blockIdx.x * 256 + threadIdx.x) * 4;        // 2097152 elems / 4
  float4 a = *(const float4*)(P0 + i);
  float4 b = *(const float4*)(P1 + i);
  union { short4_t v; __hip_bfloat16 h[4]; } u;
  u.h[0] = __float2bfloat16(a.x + b.x);
  u.h[1] = __float2bfloat16(a.y + b.y);
  u.h[2] = __float2bfloat16(a.z + b.z);
  u.h[3] = __float2bfloat16(a.w + b.w);
  *(short4_t*)(ckv + i) = u.v;
}

// ---------------- ring-3 BIG GEMM: 256x256, BK=32, 8 waves, 96 KB LDS (R13-proven) ----
template<int MODE>
__global__ __launch_bounds__(512, 2) void k_gemm8(const __hip_bfloat16* __restrict__ A,
                                                  const __hip_bfloat16* __restrict__ Bt,
                                                  int K, int nbx,
                                                  void* __restrict__ O0, void* __restrict__ O1,
                                                  void* __restrict__ O2) {
  __shared__ __align__(16) __hip_bfloat16 Al[3][256 * 32];   // 48 KB
  __shared__ __align__(16) __hip_bfloat16 Bl[3][256 * 32];   // 48 KB
  int bx = blockIdx.x % nbx, by = blockIdx.x / nbx;
  int tid = threadIdx.x, lane = tid & 63, w = tid >> 6;      // w: 0..7
  int L = lane & 15, hi = lane >> 4;
  int wr = (w >> 2) << 7;                                    // 0 or 128
  int wc = (w & 3) << 6;                                     // 0,64,128,192
  f32x4_t acc[8][4] = {};
  const __hip_bfloat16* Ag = A + (size_t)(by * 256) * K;
  const __hip_bfloat16* Bg = Bt + (size_t)(bx * 256) * K;
  int rA = w * 16 + (lane >> 2);                             // 0..127
  int cA = ((lane & 3) ^ ((lane >> 3) & 3)) * 8;
  int NT = K >> 5;

  auto stage = [&](int s) {
    int j = s % 3;
    int k0 = s << 5;
    gload_lds16(Ag + (size_t)rA * K + k0 + cA,         &Al[j][(w * 16) * 32]);
    gload_lds16(Ag + (size_t)(rA + 128) * K + k0 + cA, &Al[j][(128 + w * 16) * 32]);
    gload_lds16(Bg + (size_t)rA * K + k0 + cA,         &Bl[j][(w * 16) * 32]);
    gload_lds16(Bg + (size_t)(rA + 128) * K + k0 + cA, &Bl[j][(128 + w * 16) * 32]);
  };

  stage(0); stage(1);
  asm volatile("s_waitcnt vmcnt(4)\ns_barrier" ::: "memory");

  int hs = hi ^ ((L >> 1) & 3);
  for (int t = 0; t < NT; ++t) {
    int j = t % 3;
    short8_t af[8], bf[4];
#pragma unroll
    for (int m = 0; m < 8; ++m) af[m] = ld8(&Al[j][(wr + 16 * m + L) * 32 + 8 * hs]);
#pragma unroll
    for (int n = 0; n < 4; ++n) bf[n] = ld8(&Bl[j][(wc + 16 * n + L) * 32 + 8 * hs]);
    if (t + 2 < NT) stage(t + 2);
    __builtin_amdgcn_s_setprio(1);
#pragma unroll
    for (int m = 0; m < 8; ++m)
#pragma unroll
      for (int n = 0; n < 4; ++n)
        acc[m][n] = __builtin_amdgcn_mfma_f32_16x16x32_bf16(af[m], bf[n], acc[m][n], 0, 0, 0);
    __builtin_amdgcn_s_setprio(0);
    if (t + 2 < NT)      asm volatile("s_waitcnt vmcnt(4)\ns_barrier" ::: "memory");
    else if (t + 1 < NT) asm volatile("s_waitcnt vmcnt(0)\ns_barrier" ::: "memory");
  }

  int r0 = by * 256 + wr + 4 * hi;
  int cb = bx * 256 + wc;

  if (MODE == 2) {
    // proj1-main: cols 0-2047 q_c*SCALE -> qcb; 2048-3071 q_r rope; 3072-4095 k_r rope
    __hip_bfloat16* qcb = (__hip_bfloat16*)O0;
    __hip_bfloat16* qrb = (__hip_bfloat16*)O1;
    __hip_bfloat16* krb = (__hip_bfloat16*)O2;
    if (cb < 2048) {
      const float SCALE = 0.08838834764831845f;
#pragma unroll
      for (int m = 0; m < 8; ++m)
#pragma unroll
        for (int n = 0; n < 4; ++n)
#pragma unroll
          for (int i = 0; i < 4; ++i)
            qcb[(size_t)(r0 + 16 * m + i) * 2048 + cb + 16 * n + L] =
                __float2bfloat16(acc[m][n][i] * SCALE);
    } else {
      bool isq = cb < 3072;
      __hip_bfloat16* dst = isq ? qrb : krb;
      float osc = isq ? 0.16832169878499666f : 1.3465735902799727f;  // SCALE_ROPE*YF : YF
      int cbl = cb - (isq ? 2048 : 3072);
      float invf[2];
#pragma unroll
      for (int p = 0; p < 2; ++p) {
        float fi = (float)(16 * p + L);
        float bi = __expf(fi * -0.28782313662425574f);   // 10000^(-i/32)
        float ramp = fminf(fmaxf((fi - 1.0f) * (1.0f / 31.0f), 0.0f), 1.0f);
        invf[p] = bi * (1.0f - ramp * (31.0f / 32.0f));
      }
#pragma unroll
      for (int m = 0; m < 8; ++m)
#pragma unroll
        for (int i = 0; i < 4; ++i) {
          int row = r0 + 16 * m + i;
          float ft = (float)(row & 2047);
#pragma unroll
          for (int p = 0; p < 2; ++p) {
            float sn, cs;
            __sincosf(ft * invf[p], &sn, &cs);
            float x1 = acc[m][p][i], x2 = acc[m][p + 2][i];
            dst[(size_t)row * 1024 + cbl + 16 * p + L] =
                __float2bfloat16((x1 * cs - x2 * sn) * osc);
            dst[(size_t)row * 1024 + cbl + 32 + 16 * p + L] =
                __float2bfloat16((x2 * cs + x1 * sn) * osc);
          }
        }
    }
  } else if (MODE == 3) {
    // proj2: cols 0-2047 k_c -> kcb; 2048-4095 v_c -> vcb AND vT transposed
    __hip_bfloat16* kcb = (__hip_bfloat16*)O0;
    __hip_bfloat16* vcb = (__hip_bfloat16*)O1;
    __hip_bfloat16* vT  = (__hip_bfloat16*)O2;
    if (cb < 2048) {
#pragma unroll
      for (int m = 0; m < 8; ++m)
#pragma unroll
        for (int n = 0; n < 4; ++n)
#pragma unroll
          for (int i = 0; i < 4; ++i)
            kcb[(size_t)(r0 + 16 * m + i) * 2048 + cb + 16 * n + L] =
                __float2bfloat16(acc[m][n][i]);
    } else {
#pragma unroll
      for (int m = 0; m < 8; ++m)
#pragma unroll
        for (int n = 0; n < 4; ++n) {
          int vcol = cb - 2048 + 16 * n + L;      // 0..2047: h*128+dh
          int hh = vcol >> 7, dh = vcol & 127;
          int row0 = r0 + 16 * m;                 // 4 consecutive rows, same b
          int b = row0 >> 11, t0 = row0 & 2047;
          union { short4_t v; __hip_bfloat16 h4[4]; } pk;
#pragma unroll
          for (int i = 0; i < 4; ++i) {
            __hip_bfloat16 bv = __float2bfloat16(acc[m][n][i]);
            vcb[(size_t)(row0 + i) * 2048 + vcol] = bv;
            pk.h4[i] = bv;
          }
          *(short4_t*)(vT + ((size_t)((b * 16 + hh) * 128 + dh) * 2048 + t0)) = pk.v;
        }
    }
  }
}

// ---------------- flash-style SPARSE attention (R13 body + R9-proven Kl/Pl swizzles) ----
// Kl [64x192] chunk16-swizzled (c ^ (row&7)); Pl [4][16x64] chunk16-swizzled.
// Both formulas correctness-verified in R9 (passed, conflicts = 0). Vt staging kept.
__global__ __launch_bounds__(256) void k_attn(const __hip_bfloat16* __restrict__ qc,
                                              const __hip_bfloat16* __restrict__ kc,
                                              const __hip_bfloat16* __restrict__ vcb,
                                              const __hip_bfloat16* __restrict__ qr,
                                              const __hip_bfloat16* __restrict__ kr,
                                              const __hip_bfloat16* __restrict__ vT,
                                              __hip_bfloat16* __restrict__ ao) {
  const int T = 2048;
  int bid = blockIdx.x;
  int qt = 31 - (bid >> 5);        // true LPT: heaviest q-tiles dispatched first
  int bh = bid & 31;
  int b = bh >> 4, h = bh & 15;
  int tid = threadIdx.x, lane = tid & 63, w = tid >> 6;
  int L = lane & 15, hi = lane >> 4;
  int q0 = qt * 64;

  __shared__ __align__(16) __hip_bfloat16 Kl[64 * 192];     // 24 KB, swizzled
  __shared__ __align__(16) __hip_bfloat16 Vt[128 * 64];     // 16 KB, swizzled chunks
  __shared__ __align__(16) __hip_bfloat16 Pl[4][16 * 64];   // 8 KB, swizzled
  char* Klb = (char*)Kl;
  char* Vtb = (char*)Vt;
  char* Plb = (char*)Pl;

  const __hip_bfloat16* vTb = vT + (size_t)(b * 16 + h) * 128 * 2048;

  int qrow = q0 + w * 16 + L;
  size_t qb = (size_t)b * T + qrow;
  short8_t qf[6];
#pragma unroll
  for (int c = 0; c < 4; ++c)
    qf[c] = ld8(qc + qb * 2048 + h * 128 + 32 * c + 8 * hi);
#pragma unroll
  for (int c = 0; c < 2; ++c)
    qf[4 + c] = ld8(qr + qb * 1024 + h * 64 + 32 * c + 8 * hi);

  f32x4_t oacc[8] = {};
  float lpart[4] = {0.0f, 0.0f, 0.0f, 0.0f};

  int nd = qt - 6;

  for (int step = 0; step <= qt + 1; ++step) {
    bool compact = (step == qt + 1);
    if (compact && nd <= 0) break;
    int kt = step;
    if (!compact && kt > 1 && kt < qt - 4) continue;
    int k0 = kt * 64;

    // ---- stage K_cat (swizzled chunk16: c ^ (row&7)) ----
#pragma unroll
    for (int i = 0; i < 6; ++i) {
      int ch = i * 256 + tid;
      int rr = ch / 24;
      int c = ch % 24;
      int d = c * 8;
      int srcr = compact ? ((rr < nd) ? 64 * (2 + rr) : 0) : (k0 + rr);
      size_t krow = (size_t)b * T + srcr;
      const __hip_bfloat16* src = (d < 128)
          ? kc + krow * 2048 + h * 128 + d
          : kr + krow * 1024 + h * 64 + (d - 128);
      *(short8_t*)(Klb + rr * 384 + 16 * (c ^ (rr & 7))) = ld8(src);
    }
    // ---- stage V ----
    if (!compact) {
#pragma unroll
      for (int i = 0; i < 4; ++i) {
        int ch = i * 256 + tid;
        int row = ch >> 3, c = ch & 7;
        int swc = c ^ (row & 7);
        *(short8_t*)(Vtb + row * 128 + 16 * swc) = ld8(vTb + (size_t)row * 2048 + k0 + c * 8);
      }
    } else {
#pragma unroll
      for (int i = 0; i < 2; ++i) {
        int ch = i * 256 + tid;
        int jj = ch >> 4, d0 = (ch & 15) * 8;
        if (jj < nd) {
          union { short8_t v; __hip_bfloat16 hh[8]; } u;
          u.v = ld8(vcb + (size_t)(b * 2048 + 64 * (2 + jj)) * 2048 + h * 128 + d0);
#pragma unroll
          for (int qq = 0; qq < 8; ++qq) {
            int dh = d0 + qq;
            int swc = (jj >> 3) ^ (dh & 7);
            *(__hip_bfloat16*)(Vtb + dh * 128 + 16 * swc + 2 * (jj & 7)) = u.hh[qq];
          }
        }
      }
    }
    __syncthreads();

    // ---- S = Q_cat @ K_cat^T (swizzled Kl read) ----
    f32x4_t sacc[4] = {};
    __builtin_amdgcn_s_setprio(1);
#pragma unroll
    for (int n = 0; n < 4; ++n) {
      int row = 16 * n + L;
#pragma unroll
      for (int c = 0; c < 6; ++c) {
        short8_t bfr = *(const short8_t*)(Klb + row * 384 + 16 * ((4 * c + hi) ^ (row & 7)));
        sacc[n] = __builtin_amdgcn_mfma_f32_16x16x32_bf16(qf[c], bfr, sacc[n], 0, 0, 0);
      }
    }
    __builtin_amdgcn_s_setprio(0);

    // ---- mask + static-max softmax: P = exp(s), masked -> 0 ----
    int rbase = q0 + w * 16 + 4 * hi;
#pragma unroll
    for (int n = 0; n < 4; ++n) {
      int col = L + 16 * n;
      int k = k0 + col;
#pragma unroll
      for (int i = 0; i < 4; ++i) {
        int rq = rbase + i;
        bool ok = compact ? (col < nd)
                          : ((k <= rq) && ((rq - k <= 256) || ((k & 63) == 0) || (k < 128)));
        float e = ok ? __expf(sacc[n][i]) : 0.0f;
        lpart[i] += e;
        // P -> Pl (per-wave, swizzled); same-wave readback, no barrier needed
        int row = 4 * hi + i;
        int cc = (2 * n + (L >> 3)) ^ (row & 7);
        *(__hip_bfloat16*)(Plb + w * 2048 + row * 128 + 16 * cc + 2 * (L & 7)) =
            __float2bfloat16(e);
      }
    }

    // ---- O += P @ V ----
    __builtin_amdgcn_s_setprio(1);
#pragma unroll
    for (int ks = 0; ks < 2; ++ks) {
      short8_t pa = *(const short8_t*)(Plb + w * 2048 + L * 128 +
                                       16 * ((4 * ks + hi) ^ (L & 7)));
#pragma unroll
      for (int n = 0; n < 8; ++n) {
        int vrow = 16 * n + L;
        int chunk = (4 * ks + hi) ^ (vrow & 7);
        short8_t bv = *(const short8_t*)(Vtb + vrow * 128 + 16 * chunk);
        oacc[n] = __builtin_amdgcn_mfma_f32_16x16x32_bf16(pa, bv, oacc[n], 0, 0, 0);
      }
    }
    __builtin_amdgcn_s_setprio(0);
    __syncthreads();   // protect Kl/Vt before next tile's staging
  }

  for (int d = 1; d < 16; d <<= 1)
#pragma unroll
    for (int i = 0; i < 4; ++i) lpart[i] += __shfl_xor(lpart[i], d, 64);

#pragma unroll
  for (int n = 0; n < 8; ++n)
#pragma unroll
    for (int i = 0; i < 4; ++i) {
      int rq = q0 + w * 16 + 4 * hi + i;
      int cdh = 16 * n + L;
      float v = oacc[n][i] / lpart[i];
      ao[((size_t)b * T + rq) * 2048 + h * 128 + cdh] = __float2bfloat16(v);
    }
}

// ---------------- host ----------------
extern "C" void kernel_launch(void* const* d_in, const int* in_sizes, int n_in,
                              void* d_out, int out_size, void* d_ws, size_t ws_size,
                              hipStream_t stream) {
  const float* x     = (const float*)d_in[0];
  const float* w_q   = (const float*)d_in[1];
  const float* w_dkv = (const float*)d_in[2];
  const float* w_uk  = (const float*)d_in[3];
  const float* w_uv  = (const float*)d_in[4];
  const float* w_qp  = (const float*)d_in[5];
  const float* w_kp  = (const float*)d_in[6];
  const float* w_o   = (const float*)d_in[7];
  float* out = (float*)d_out;

  char* ws = (char*)d_ws;
  size_t off = 0;
  auto alloc = [&](size_t elems) {
    __hip_bfloat16* p = (__hip_bfloat16*)(ws + off);
    off += ((elems * 2 + 255) & ~(size_t)255);
    return p;
  };
  __hip_bfloat16* xb  = alloc(8388608);            // x bf16 [4096][2048]
  __hip_bfloat16* Bt1 = alloc(4608UL * 2048);      // [wq^T; wqp^T; wkp^T; wdkv^T]
  __hip_bfloat16* Bt2 = alloc(4096UL * 512);       // [wuk^T; wuv^T]
  __hip_bfloat16* woT = alloc(4194304);
  __hip_bfloat16* qcb = alloc(8388608);
  __hip_bfloat16* ckv = alloc(2097152);
  __hip_bfloat16* kcb = alloc(8388608);
  __hip_bfloat16* vcb = alloc(8388608);
  __hip_bfloat16* qrb = alloc(4194304);
  __hip_bfloat16* krb = alloc(4194304);
  __hip_bfloat16* aob = alloc(8388608);            // attn out; reused as wdkv f32 partials
  __hip_bfloat16* vT  = alloc(8388608);            // [32][128][2048]

  float* P0 = (float*)aob;
  float* P1 = P0 + 2097152;

  k_prep<<<7936, 256, 0, stream>>>(x, xb, w_q, w_qp, w_kp, w_dkv, w_uk, w_uv, w_o,
                                   Bt1, Bt2, woT);

  k_gemm_ks<<<256, 256, 0, stream>>>(xb, Bt1 + 4096UL * 2048, 2048, 4, P0, P1);
  k_addc<<<2048, 256, 0, stream>>>(P0, P1, ckv);

  k_gemm8<2><<<16 * 16, 512, 0, stream>>>(xb, Bt1, 2048, 16, qcb, qrb, krb);
  k_gemm8<3><<<16 * 16, 512, 0, stream>>>(ckv, Bt2, 512, 16, kcb, vcb, vT);

  k_attn<<<1024, 256, 0, stream>>>(qcb, kcb, vcb, qrb, krb, vT, aob);

  k_gemm2<1><<<16 * 32, 256, 0, stream>>>(aob, woT, 2048, 16, out, 1.0f);
}

// Round 16
// 244.478 us; speedup vs baseline: 1.0254x; 1.0163x over previous
//
#include <hip/hip_runtime.h>
#include <hip/hip_bf16.h>
#include <cstdint>

typedef __attribute__((ext_vector_type(8))) short short8_t;   // 8 x bf16
typedef __attribute__((ext_vector_type(4))) short short4_t;   // 4 x bf16
typedef __attribute__((ext_vector_type(4))) float f32x4_t;    // MFMA acc

#define AS1 __attribute__((address_space(1)))
#define AS3 __attribute__((address_space(3)))

__device__ __forceinline__ void gload_lds16(const void* g, void* l) {
  __builtin_amdgcn_global_load_lds((const AS1 void*)g, (AS3 void*)l, 16, 0, 0);
}

__device__ __forceinline__ short8_t ld8(const __hip_bfloat16* p) {
  return *(const short8_t*)p;
}

// ---------------- fused prep: convert x + transpose all 7 weights ----------------
__global__ __launch_bounds__(256) void k_prep(
    const float* __restrict__ x, __hip_bfloat16* __restrict__ xb,
    const float* __restrict__ wq,  const float* __restrict__ wqp,
    const float* __restrict__ wkp, const float* __restrict__ wdkv,
    const float* __restrict__ wuk, const float* __restrict__ wuv,
    const float* __restrict__ wo,
    __hip_bfloat16* __restrict__ Bt1, __hip_bfloat16* __restrict__ Bt2,
    __hip_bfloat16* __restrict__ woT) {
  __shared__ float t[64][65];
  int bid = blockIdx.x;
  if (bid < 4096) {
    int i = (bid * 256 + threadIdx.x) * 8;
    union { short8_t v; __hip_bfloat16 h[8]; } u;
#pragma unroll
    for (int j = 0; j < 8; ++j) u.h[j] = __float2bfloat16(x[i + j]);
    *(short8_t*)(xb + i) = u.v;
    return;
  }
  bid -= 4096;
  const float* in; __hip_bfloat16* out; int R, C, tile;
  if (bid < 1024)      { in = wq;   out = Bt1;                 R = 2048; C = 2048; tile = bid; }
  else if (bid < 1536) { in = wqp;  out = Bt1 + 2048UL * 2048; R = 2048; C = 1024; tile = bid - 1024; }
  else if (bid < 2048) { in = wkp;  out = Bt1 + 3072UL * 2048; R = 2048; C = 1024; tile = bid - 1536; }
  else if (bid < 2304) { in = wdkv; out = Bt1 + 4096UL * 2048; R = 2048; C = 512;  tile = bid - 2048; }
  else if (bid < 2560) { in = wuk;  out = Bt2;                 R = 512;  C = 2048; tile = bid - 2304; }
  else if (bid < 2816) { in = wuv;  out = Bt2 + 2048UL * 512;  R = 512;  C = 2048; tile = bid - 2560; }
  else                 { in = wo;   out = woT;                 R = 2048; C = 2048; tile = bid - 2816; }
  int nct = C >> 6;
  int ct = tile % nct, rt = tile / nct;
  int r0 = rt << 6, c0 = ct << 6;
#pragma unroll
  for (int i = 0; i < 16; ++i) {
    int idx = i * 256 + threadIdx.x;
    int r = idx >> 6, c = idx & 63;
    t[r][c] = in[(size_t)(r0 + r) * C + c0 + c];
  }
  __syncthreads();
#pragma unroll
  for (int i = 0; i < 16; ++i) {
    int idx = i * 256 + threadIdx.x;
    int c = idx >> 6, r = idx & 63;
    out[(size_t)(c0 + c) * R + r0 + r] = __float2bfloat16(t[r][c]);
  }
}

// ---------------- ring-3 pipelined GEMM (R5-proven): 128x128, 4 waves, 48 KB LDS ----
// MODE 1: f32 out.
template<int MODE>
__global__ __launch_bounds__(256) void k_gemm2(const __hip_bfloat16* __restrict__ A,
                                               const __hip_bfloat16* __restrict__ Bt,
                                               int K, int nbx,
                                               void* __restrict__ O0, float alpha) {
  __shared__ __align__(16) __hip_bfloat16 Al[3][128 * 32];
  __shared__ __align__(16) __hip_bfloat16 Bl[3][128 * 32];
  int bx = blockIdx.x % nbx, by = blockIdx.x / nbx;
  int tid = threadIdx.x, lane = tid & 63, w = tid >> 6;
  int L = lane & 15, hi = lane >> 4;
  int wr = (w >> 1) << 6, wc = (w & 1) << 6;
  f32x4_t acc[4][4] = {};
  const __hip_bfloat16* Ag = A + (size_t)(by * 128) * K;
  const __hip_bfloat16* Bg = Bt + (size_t)(bx * 128) * K;
  int rA = w * 16 + (lane >> 2);
  int cA = ((lane & 3) ^ ((lane >> 3) & 3)) * 8;       // inverse-swizzled source chunk
  int NT = K >> 5;

  auto stage = [&](int s) {
    int j = s % 3;
    int k0 = s << 5;
    gload_lds16(Ag + (size_t)rA * K + k0 + cA,        &Al[j][(w * 16) * 32]);
    gload_lds16(Ag + (size_t)(rA + 64) * K + k0 + cA, &Al[j][(64 + w * 16) * 32]);
    gload_lds16(Bg + (size_t)rA * K + k0 + cA,        &Bl[j][(w * 16) * 32]);
    gload_lds16(Bg + (size_t)(rA + 64) * K + k0 + cA, &Bl[j][(64 + w * 16) * 32]);
  };

  stage(0); stage(1);
  asm volatile("s_waitcnt vmcnt(4)\ns_barrier" ::: "memory");

  int hs = hi ^ ((L >> 1) & 3);
  for (int t = 0; t < NT; ++t) {
    int j = t % 3;
    short8_t af[4], bf[4];
#pragma unroll
    for (int m = 0; m < 4; ++m) af[m] = ld8(&Al[j][(wr + 16 * m + L) * 32 + 8 * hs]);
#pragma unroll
    for (int n = 0; n < 4; ++n) bf[n] = ld8(&Bl[j][(wc + 16 * n + L) * 32 + 8 * hs]);
    if (t + 2 < NT) stage(t + 2);
    __builtin_amdgcn_s_setprio(1);
#pragma unroll
    for (int m = 0; m < 4; ++m)
#pragma unroll
      for (int n = 0; n < 4; ++n)
        acc[m][n] = __builtin_amdgcn_mfma_f32_16x16x32_bf16(af[m], bf[n], acc[m][n], 0, 0, 0);
    __builtin_amdgcn_s_setprio(0);
    if (t + 2 < NT)      asm volatile("s_waitcnt vmcnt(4)\ns_barrier" ::: "memory");
    else if (t + 1 < NT) asm volatile("s_waitcnt vmcnt(0)\ns_barrier" ::: "memory");
  }

  int r0 = by * 128 + wr + 4 * hi;
  int c0 = bx * 128 + wc;
  size_t N = (size_t)nbx << 7;
  float* C = (float*)O0;
#pragma unroll
  for (int m = 0; m < 4; ++m)
#pragma unroll
    for (int n = 0; n < 4; ++n)
#pragma unroll
      for (int i = 0; i < 4; ++i)
        C[(size_t)(r0 + 16 * m + i) * N + c0 + 16 * n + L] = acc[m][n][i] * alpha;
}

// ---------------- split-K ring-3 GEMM for wdkv: 256 blocks = 2 K-parts x 128 tiles ----
__global__ __launch_bounds__(256) void k_gemm_ks(const __hip_bfloat16* __restrict__ A,
                                                 const __hip_bfloat16* __restrict__ Bt,
                                                 int lda, int nbx,
                                                 float* __restrict__ P0,
                                                 float* __restrict__ P1) {
  __shared__ __align__(16) __hip_bfloat16 Al[3][128 * 32];
  __shared__ __align__(16) __hip_bfloat16 Bl[3][128 * 32];
  int part = blockIdx.x >> 7;
  int id = blockIdx.x & 127;
  int bx = id % nbx, by = id / nbx;
  int tid = threadIdx.x, lane = tid & 63, w = tid >> 6;
  int L = lane & 15, hi = lane >> 4;
  int wr = (w >> 1) << 6, wc = (w & 1) << 6;
  f32x4_t acc[4][4] = {};
  const __hip_bfloat16* Ag = A + (size_t)(by * 128) * lda + part * 1024;
  const __hip_bfloat16* Bg = Bt + (size_t)(bx * 128) * lda + part * 1024;
  int rA = w * 16 + (lane >> 2);
  int cA = ((lane & 3) ^ ((lane >> 3) & 3)) * 8;
  const int NT = 32;                                    // K=1024

  auto stage = [&](int s) {
    int j = s % 3;
    int k0 = s << 5;
    gload_lds16(Ag + (size_t)rA * lda + k0 + cA,        &Al[j][(w * 16) * 32]);
    gload_lds16(Ag + (size_t)(rA + 64) * lda + k0 + cA, &Al[j][(64 + w * 16) * 32]);
    gload_lds16(Bg + (size_t)rA * lda + k0 + cA,        &Bl[j][(w * 16) * 32]);
    gload_lds16(Bg + (size_t)(rA + 64) * lda + k0 + cA, &Bl[j][(64 + w * 16) * 32]);
  };

  stage(0); stage(1);
  asm volatile("s_waitcnt vmcnt(4)\ns_barrier" ::: "memory");

  int hs = hi ^ ((L >> 1) & 3);
  for (int t = 0; t < NT; ++t) {
    int j = t % 3;
    short8_t af[4], bf[4];
#pragma unroll
    for (int m = 0; m < 4; ++m) af[m] = ld8(&Al[j][(wr + 16 * m + L) * 32 + 8 * hs]);
#pragma unroll
    for (int n = 0; n < 4; ++n) bf[n] = ld8(&Bl[j][(wc + 16 * n + L) * 32 + 8 * hs]);
    if (t + 2 < NT) stage(t + 2);
    __builtin_amdgcn_s_setprio(1);
#pragma unroll
    for (int m = 0; m < 4; ++m)
#pragma unroll
      for (int n = 0; n < 4; ++n)
        acc[m][n] = __builtin_amdgcn_mfma_f32_16x16x32_bf16(af[m], bf[n], acc[m][n], 0, 0, 0);
    __builtin_amdgcn_s_setprio(0);
    if (t + 2 < NT)      asm volatile("s_waitcnt vmcnt(4)\ns_barrier" ::: "memory");
    else if (t + 1 < NT) asm volatile("s_waitcnt vmcnt(0)\ns_barrier" ::: "memory");
  }

  float* C = part ? P1 : P0;
  int r0 = by * 128 + wr + 4 * hi;
  int c0 = bx * 128 + wc;
#pragma unroll
  for (int m = 0; m < 4; ++m)
#pragma unroll
    for (int n = 0; n < 4; ++n)
#pragma unroll
      for (int i = 0; i < 4; ++i)
        C[(size_t)(r0 + 16 * m + i) * 512 + c0 + 16 * n + L] = acc[m][n][i];
}

// ---------------- combine split-K partials -> bf16 ckv ----------------
__global__ __launch_bounds__(256) void k_addc(const float* __restrict__ P0,
                                              const float* __restrict__ P1,
                                              __hip_bfloat16* __restrict__ ckv) {
  int i = (blockIdx.x * 256 + threadIdx.x) * 4;        // 2097152 elems / 4
  float4 a = *(const float4*)(P0 + i);
  float4 b = *(const float4*)(P1 + i);
  union { short4_t v; __hip_bfloat16 h[4]; } u;
  u.h[0] = __float2bfloat16(a.x + b.x);
  u.h[1] = __float2bfloat16(a.y + b.y);
  u.h[2] = __float2bfloat16(a.z + b.z);
  u.h[3] = __float2bfloat16(a.w + b.w);
  *(short4_t*)(ckv + i) = u.v;
}

// ---------------- ring-3 BIG GEMM: 256x256, BK=32, 8 waves, 96 KB LDS (R13-proven) ----
template<int MODE>
__global__ __launch_bounds__(512, 2) void k_gemm8(const __hip_bfloat16* __restrict__ A,
                                                  const __hip_bfloat16* __restrict__ Bt,
                                                  int K, int nbx,
                                                  void* __restrict__ O0, void* __restrict__ O1,
                                                  void* __restrict__ O2) {
  __shared__ __align__(16) __hip_bfloat16 Al[3][256 * 32];   // 48 KB
  __shared__ __align__(16) __hip_bfloat16 Bl[3][256 * 32];   // 48 KB
  int bx = blockIdx.x % nbx, by = blockIdx.x / nbx;
  int tid = threadIdx.x, lane = tid & 63, w = tid >> 6;      // w: 0..7
  int L = lane & 15, hi = lane >> 4;
  int wr = (w >> 2) << 7;                                    // 0 or 128
  int wc = (w & 3) << 6;                                     // 0,64,128,192
  f32x4_t acc[8][4] = {};
  const __hip_bfloat16* Ag = A + (size_t)(by * 256) * K;
  const __hip_bfloat16* Bg = Bt + (size_t)(bx * 256) * K;
  int rA = w * 16 + (lane >> 2);                             // 0..127
  int cA = ((lane & 3) ^ ((lane >> 3) & 3)) * 8;
  int NT = K >> 5;

  auto stage = [&](int s) {
    int j = s % 3;
    int k0 = s << 5;
    gload_lds16(Ag + (size_t)rA * K + k0 + cA,         &Al[j][(w * 16) * 32]);
    gload_lds16(Ag + (size_t)(rA + 128) * K + k0 + cA, &Al[j][(128 + w * 16) * 32]);
    gload_lds16(Bg + (size_t)rA * K + k0 + cA,         &Bl[j][(w * 16) * 32]);
    gload_lds16(Bg + (size_t)(rA + 128) * K + k0 + cA, &Bl[j][(128 + w * 16) * 32]);
  };

  stage(0); stage(1);
  asm volatile("s_waitcnt vmcnt(4)\ns_barrier" ::: "memory");

  int hs = hi ^ ((L >> 1) & 3);
  for (int t = 0; t < NT; ++t) {
    int j = t % 3;
    short8_t af[8], bf[4];
#pragma unroll
    for (int m = 0; m < 8; ++m) af[m] = ld8(&Al[j][(wr + 16 * m + L) * 32 + 8 * hs]);
#pragma unroll
    for (int n = 0; n < 4; ++n) bf[n] = ld8(&Bl[j][(wc + 16 * n + L) * 32 + 8 * hs]);
    if (t + 2 < NT) stage(t + 2);
    __builtin_amdgcn_s_setprio(1);
#pragma unroll
    for (int m = 0; m < 8; ++m)
#pragma unroll
      for (int n = 0; n < 4; ++n)
        acc[m][n] = __builtin_amdgcn_mfma_f32_16x16x32_bf16(af[m], bf[n], acc[m][n], 0, 0, 0);
    __builtin_amdgcn_s_setprio(0);
    if (t + 2 < NT)      asm volatile("s_waitcnt vmcnt(4)\ns_barrier" ::: "memory");
    else if (t + 1 < NT) asm volatile("s_waitcnt vmcnt(0)\ns_barrier" ::: "memory");
  }

  int r0 = by * 256 + wr + 4 * hi;
  int cb = bx * 256 + wc;

  if (MODE == 2) {
    // proj1-main: cols 0-2047 q_c*SCALE -> qcb; 2048-3071 q_r rope; 3072-4095 k_r rope
    __hip_bfloat16* qcb = (__hip_bfloat16*)O0;
    __hip_bfloat16* qrb = (__hip_bfloat16*)O1;
    __hip_bfloat16* krb = (__hip_bfloat16*)O2;
    if (cb < 2048) {
      const float SCALE = 0.08838834764831845f;
#pragma unroll
      for (int m = 0; m < 8; ++m)
#pragma unroll
        for (int n = 0; n < 4; ++n)
#pragma unroll
          for (int i = 0; i < 4; ++i)
            qcb[(size_t)(r0 + 16 * m + i) * 2048 + cb + 16 * n + L] =
                __float2bfloat16(acc[m][n][i] * SCALE);
    } else {
      bool isq = cb < 3072;
      __hip_bfloat16* dst = isq ? qrb : krb;
      float osc = isq ? 0.16832169878499666f : 1.3465735902799727f;  // SCALE_ROPE*YF : YF
      int cbl = cb - (isq ? 2048 : 3072);
      float invf[2];
#pragma unroll
      for (int p = 0; p < 2; ++p) {
        float fi = (float)(16 * p + L);
        float bi = __expf(fi * -0.28782313662425574f);   // 10000^(-i/32)
        float ramp = fminf(fmaxf((fi - 1.0f) * (1.0f / 31.0f), 0.0f), 1.0f);
        invf[p] = bi * (1.0f - ramp * (31.0f / 32.0f));
      }
#pragma unroll
      for (int m = 0; m < 8; ++m)
#pragma unroll
        for (int i = 0; i < 4; ++i) {
          int row = r0 + 16 * m + i;
          float ft = (float)(row & 2047);
#pragma unroll
          for (int p = 0; p < 2; ++p) {
            float sn, cs;
            __sincosf(ft * invf[p], &sn, &cs);
            float x1 = acc[m][p][i], x2 = acc[m][p + 2][i];
            dst[(size_t)row * 1024 + cbl + 16 * p + L] =
                __float2bfloat16((x1 * cs - x2 * sn) * osc);
            dst[(size_t)row * 1024 + cbl + 32 + 16 * p + L] =
                __float2bfloat16((x2 * cs + x1 * sn) * osc);
          }
        }
    }
  } else if (MODE == 3) {
    // proj2: cols 0-2047 k_c -> kcb; 2048-4095 v_c -> vcb AND vT transposed
    __hip_bfloat16* kcb = (__hip_bfloat16*)O0;
    __hip_bfloat16* vcb = (__hip_bfloat16*)O1;
    __hip_bfloat16* vT  = (__hip_bfloat16*)O2;
    if (cb < 2048) {
#pragma unroll
      for (int m = 0; m < 8; ++m)
#pragma unroll
        for (int n = 0; n < 4; ++n)
#pragma unroll
          for (int i = 0; i < 4; ++i)
            kcb[(size_t)(r0 + 16 * m + i) * 2048 + cb + 16 * n + L] =
                __float2bfloat16(acc[m][n][i]);
    } else {
#pragma unroll
      for (int m = 0; m < 8; ++m)
#pragma unroll
        for (int n = 0; n < 4; ++n) {
          int vcol = cb - 2048 + 16 * n + L;      // 0..2047: h*128+dh
          int hh = vcol >> 7, dh = vcol & 127;
          int row0 = r0 + 16 * m;                 // 4 consecutive rows, same b
          int b = row0 >> 11, t0 = row0 & 2047;
          union { short4_t v; __hip_bfloat16 h4[4]; } pk;
#pragma unroll
          for (int i = 0; i < 4; ++i) {
            __hip_bfloat16 bv = __float2bfloat16(acc[m][n][i]);
            vcb[(size_t)(row0 + i) * 2048 + vcol] = bv;
            pk.h4[i] = bv;
          }
          *(short4_t*)(vT + ((size_t)((b * 16 + hh) * 128 + dh) * 2048 + t0)) = pk.v;
        }
    }
  }
}

// ---------------- flash-style SPARSE attention (R15 body, gload_lds staging) ----
// K/V staged via global_load_lds: LINEAR LDS dest (wave-uniform base + lane*16),
// inverse swizzle applied to the SOURCE chunk index (rule 21). Resulting LDS
// content is byte-identical to R15's swizzled layout; all reads unchanged.
__global__ __launch_bounds__(256) void k_attn(const __hip_bfloat16* __restrict__ qc,
                                              const __hip_bfloat16* __restrict__ kc,
                                              const __hip_bfloat16* __restrict__ vcb,
                                              const __hip_bfloat16* __restrict__ qr,
                                              const __hip_bfloat16* __restrict__ kr,
                                              const __hip_bfloat16* __restrict__ vT,
                                              __hip_bfloat16* __restrict__ ao) {
  const int T = 2048;
  int bid = blockIdx.x;
  int qt = 31 - (bid >> 5);        // true LPT: heaviest q-tiles dispatched first
  int bh = bid & 31;
  int b = bh >> 4, h = bh & 15;
  int tid = threadIdx.x, lane = tid & 63, w = tid >> 6;
  int L = lane & 15, hi = lane >> 4;
  int q0 = qt * 64;

  __shared__ __align__(16) __hip_bfloat16 Kl[64 * 192];     // 24 KB, swizzled content
  __shared__ __align__(16) __hip_bfloat16 Vt[128 * 64];     // 16 KB, swizzled content
  __shared__ __align__(16) __hip_bfloat16 Pl[4][16 * 64];   // 8 KB, swizzled
  char* Klb = (char*)Kl;
  char* Vtb = (char*)Vt;
  char* Plb = (char*)Pl;

  const __hip_bfloat16* vTb = vT + (size_t)(b * 16 + h) * 128 * 2048;

  int qrow = q0 + w * 16 + L;
  size_t qb = (size_t)b * T + qrow;
  short8_t qf[6];
#pragma unroll
  for (int c = 0; c < 4; ++c)
    qf[c] = ld8(qc + qb * 2048 + h * 128 + 32 * c + 8 * hi);
#pragma unroll
  for (int c = 0; c < 2; ++c)
    qf[4 + c] = ld8(qr + qb * 1024 + h * 64 + 32 * c + 8 * hi);

  f32x4_t oacc[8] = {};
  float lpart[4] = {0.0f, 0.0f, 0.0f, 0.0f};

  int nd = qt - 6;

  for (int step = 0; step <= qt + 1; ++step) {
    bool compact = (step == qt + 1);
    if (compact && nd <= 0) break;
    int kt = step;
    if (!compact && kt > 1 && kt < qt - 4) continue;
    int k0 = kt * 64;

    // ---- stage K_cat via gload_lds: linear dest, source chunk = cs ^ (rr&7) ----
#pragma unroll
    for (int i = 0; i < 6; ++i) {
      int o = i * 256 + tid;          // linear chunk index (row rr, stored chunk cs)
      int rr = o / 24;
      int cs = o % 24;
      int c = cs ^ (rr & 7);          // source chunk (XOR stays within 8-block)
      int d = c * 8;
      int srcr = compact ? ((rr < nd) ? 64 * (2 + rr) : 0) : (k0 + rr);
      size_t krow = (size_t)b * T + srcr;
      const __hip_bfloat16* src = (d < 128)
          ? kc + krow * 2048 + h * 128 + d
          : kr + krow * 1024 + h * 64 + (d - 128);
      gload_lds16(src, Klb + (i * 256 + w * 64) * 16);
    }
    // ---- stage V ----
    if (!compact) {
#pragma unroll
      for (int i = 0; i < 4; ++i) {
        int o = i * 256 + tid;
        int row = o >> 3, cs = o & 7;
        int c = cs ^ (row & 7);       // source chunk
        gload_lds16(vTb + (size_t)row * 2048 + k0 + c * 8,
                    Vtb + (i * 256 + w * 64) * 16);
      }
    } else {
      // compact V gather: register path (scattered sub-chunk writes)
#pragma unroll
      for (int i = 0; i < 2; ++i) {
        int ch = i * 256 + tid;
        int jj = ch >> 4, d0 = (ch & 15) * 8;
        if (jj < nd) {
          union { short8_t v; __hip_bfloat16 hh[8]; } u;
          u.v = ld8(vcb + (size_t)(b * 2048 + 64 * (2 + jj)) * 2048 + h * 128 + d0);
#pragma unroll
          for (int qq = 0; qq < 8; ++qq) {
            int dh = d0 + qq;
            int swc = (jj >> 3) ^ (dh & 7);
            *(__hip_bfloat16*)(Vtb + dh * 128 + 16 * swc + 2 * (jj & 7)) = u.hh[qq];
          }
        }
      }
    }
    __syncthreads();   // drains vmcnt (gload_lds) + lgkm before any reads

    // ---- S = Q_cat @ K_cat^T (swizzled Kl read) ----
    f32x4_t sacc[4] = {};
    __builtin_amdgcn_s_setprio(1);
#pragma unroll
    for (int n = 0; n < 4; ++n) {
      int row = 16 * n + L;
#pragma unroll
      for (int c = 0; c < 6; ++c) {
        short8_t bfr = *(const short8_t*)(Klb + row * 384 + 16 * ((4 * c + hi) ^ (row & 7)));
        sacc[n] = __builtin_amdgcn_mfma_f32_16x16x32_bf16(qf[c], bfr, sacc[n], 0, 0, 0);
      }
    }
    __builtin_amdgcn_s_setprio(0);

    // ---- mask + static-max softmax: P = exp(s), masked -> 0 ----
    int rbase = q0 + w * 16 + 4 * hi;
#pragma unroll
    for (int n = 0; n < 4; ++n) {
      int col = L + 16 * n;
      int k = k0 + col;
#pragma unroll
      for (int i = 0; i < 4; ++i) {
        int rq = rbase + i;
        bool ok = compact ? (col < nd)
                          : ((k <= rq) && ((rq - k <= 256) || ((k & 63) == 0) || (k < 128)));
        float e = ok ? __expf(sacc[n][i]) : 0.0f;
        lpart[i] += e;
        int row = 4 * hi + i;
        int cc = (2 * n + (L >> 3)) ^ (row & 7);
        *(__hip_bfloat16*)(Plb + w * 2048 + row * 128 + 16 * cc + 2 * (L & 7)) =
            __float2bfloat16(e);
      }
    }

    // ---- O += P @ V ----
    __builtin_amdgcn_s_setprio(1);
#pragma unroll
    for (int ks = 0; ks < 2; ++ks) {
      short8_t pa = *(const short8_t*)(Plb + w * 2048 + L * 128 +
                                       16 * ((4 * ks + hi) ^ (L & 7)));
#pragma unroll
      for (int n = 0; n < 8; ++n) {
        int vrow = 16 * n + L;
        int chunk = (4 * ks + hi) ^ (vrow & 7);
        short8_t bv = *(const short8_t*)(Vtb + vrow * 128 + 16 * chunk);
        oacc[n] = __builtin_amdgcn_mfma_f32_16x16x32_bf16(pa, bv, oacc[n], 0, 0, 0);
      }
    }
    __builtin_amdgcn_s_setprio(0);
    __syncthreads();   // protect Kl/Vt before next tile's staging
  }

  for (int d = 1; d < 16; d <<= 1)
#pragma unroll
    for (int i = 0; i < 4; ++i) lpart[i] += __shfl_xor(lpart[i], d, 64);

#pragma unroll
  for (int n = 0; n < 8; ++n)
#pragma unroll
    for (int i = 0; i < 4; ++i) {
      int rq = q0 + w * 16 + 4 * hi + i;
      int cdh = 16 * n + L;
      float v = oacc[n][i] / lpart[i];
      ao[((size_t)b * T + rq) * 2048 + h * 128 + cdh] = __float2bfloat16(v);
    }
}

// ---------------- host ----------------
extern "C" void kernel_launch(void* const* d_in, const int* in_sizes, int n_in,
                              void* d_out, int out_size, void* d_ws, size_t ws_size,
                              hipStream_t stream) {
  const float* x     = (const float*)d_in[0];
  const float* w_q   = (const float*)d_in[1];
  const float* w_dkv = (const float*)d_in[2];
  const float* w_uk  = (const float*)d_in[3];
  const float* w_uv  = (const float*)d_in[4];
  const float* w_qp  = (const float*)d_in[5];
  const float* w_kp  = (const float*)d_in[6];
  const float* w_o   = (const float*)d_in[7];
  float* out = (float*)d_out;

  char* ws = (char*)d_ws;
  size_t off = 0;
  auto alloc = [&](size_t elems) {
    __hip_bfloat16* p = (__hip_bfloat16*)(ws + off);
    off += ((elems * 2 + 255) & ~(size_t)255);
    return p;
  };
  __hip_bfloat16* xb  = alloc(8388608);            // x bf16 [4096][2048]
  __hip_bfloat16* Bt1 = alloc(4608UL * 2048);      // [wq^T; wqp^T; wkp^T; wdkv^T]
  __hip_bfloat16* Bt2 = alloc(4096UL * 512);       // [wuk^T; wuv^T]
  __hip_bfloat16* woT = alloc(4194304);
  __hip_bfloat16* qcb = alloc(8388608);
  __hip_bfloat16* ckv = alloc(2097152);
  __hip_bfloat16* kcb = alloc(8388608);
  __hip_bfloat16* vcb = alloc(8388608);
  __hip_bfloat16* qrb = alloc(4194304);
  __hip_bfloat16* krb = alloc(4194304);
  __hip_bfloat16* aob = alloc(8388608);            // attn out; reused as wdkv f32 partials
  __hip_bfloat16* vT  = alloc(8388608);            // [32][128][2048]

  float* P0 = (float*)aob;
  float* P1 = P0 + 2097152;

  k_prep<<<7936, 256, 0, stream>>>(x, xb, w_q, w_qp, w_kp, w_dkv, w_uk, w_uv, w_o,
                                   Bt1, Bt2, woT);

  k_gemm_ks<<<256, 256, 0, stream>>>(xb, Bt1 + 4096UL * 2048, 2048, 4, P0, P1);
  k_addc<<<2048, 256, 0, stream>>>(P0, P1, ckv);

  k_gemm8<2><<<16 * 16, 512, 0, stream>>>(xb, Bt1, 2048, 16, qcb, qrb, krb);
  k_gemm8<3><<<16 * 16, 512, 0, stream>>>(ckv, Bt2, 512, 16, kcb, vcb, vT);

  k_attn<<<1024, 256, 0, stream>>>(qcb, kcb, vcb, qrb, krb, vT, aob);

  k_gemm2<1><<<16 * 32, 256, 0, stream>>>(aob, woT, 2048, 16, out, 1.0f);
}